// Round 4
// baseline (71.712 us; speedup 1.0000x reference)
//
#include <hip/hip_runtime.h>
#include <math.h>

// Problem constants (hardcoded in the reference layer)
#define B_ROWS 32768
#define DIM    1024
#define NC     7
#define D4     (DIM/4)
#define RPB    32          // rows per block in the main pass
#define BLK    256

#define ALPHA_C   0.5f
#define LAMBDA2_C 0.5f

// ws layout (floats):
//  [0]          pair_dist
//  [1..7]       coef1[7]
//  [8..56]      coef2[49]  (row-major, diag = 0)
//  [64..7231]   featsum[7*1024]
//  [7232..7238] counts[7] (float)
#define WS_PD     0
#define WS_COEF1  1
#define WS_COEF2  8
#define WS_FSUM   64
#define WS_CNT    (64 + NC*DIM)

__device__ __forceinline__ float waveReduceSum(float v) {
#pragma unroll
    for (int o = 32; o > 0; o >>= 1) v += __shfl_xor(v, o, 64);
    return v;
}

// ---------------------------------------------------------------------------
// Kernel 0: centers-only prologue. 1 block.
// ---------------------------------------------------------------------------
__global__ __launch_bounds__(BLK)
void prep_kernel(const float4* __restrict__ centers4, float* __restrict__ ws) {
    __shared__ __align__(16) float cen[NC * DIM];
    __shared__ float G[NC * NC];
    const int tid = threadIdx.x;

    // zero the accumulation region (featsum + counts)
    for (int i = tid; i < NC * DIM + 8; i += BLK) ws[WS_FSUM + i] = 0.0f;

    // stage centers into LDS
    for (int i = tid; i < NC * D4; i += BLK) ((float4*)cen)[i] = centers4[i];
    __syncthreads();

    const int wid = tid >> 6, lane = tid & 63;
#pragma unroll 1
    for (int k = 0; k < 7; ++k) {
        const int p = wid * 7 + k;
        int j = 0, q = p;
        while (q >= 7 - j) { q -= 7 - j; ++j; }
        const int m = j + q;

        float s = 0.0f;
#pragma unroll
        for (int c4 = 0; c4 < 4; ++c4) {
            const float4 a = *(const float4*)&cen[j * DIM + (lane + c4 * 64) * 4];
            const float4 b = *(const float4*)&cen[m * DIM + (lane + c4 * 64) * 4];
            s += a.x * b.x + a.y * b.y + a.z * b.z + a.w * b.w;
        }
        s = waveReduceSum(s);
        if (lane == 0) { G[j * 7 + m] = s; G[m * 7 + j] = s; }
    }
    __syncthreads();

    if (tid == 0) {
        float inv[7], sumInv = 0.0f;
#pragma unroll
        for (int j = 0; j < 7; ++j) {
            inv[j] = 1.0f / sqrtf(G[j * 7 + j]);
            sumInv += inv[j];
        }
        float pdsum = 0.0f;
#pragma unroll
        for (int j = 0; j < 7; ++j) {
            ws[WS_COEF1 + j] = inv[j] * (sumInv - inv[j]);
#pragma unroll
            for (int m = 0; m < 7; ++m) {
                if (m == j) { ws[WS_COEF2 + j * 7 + m] = 0.0f; continue; }
                const float g = G[j * 7 + m];
                pdsum += g * inv[j] * inv[m] + 1.0f;
                ws[WS_COEF2 + j * 7 + m] = g * inv[j] * inv[m] * inv[m] * inv[m];
            }
        }
        ws[WS_PD] = LAMBDA2_C * pdsum;
    }
}

// ---------------------------------------------------------------------------
// Kernel 1: main streaming pass, 1024 blocks x 32 rows.
// Hand software-pipelined: two named 8xfloat4 register buffers; batch k+1's
// loads issue BEFORE batch k's compute, so every wave keeps 8 dwordx4 loads
// in flight during its compute phase. Batch 0's loads issue before LDS
// staging to overlap the __syncthreads.
// ---------------------------------------------------------------------------
#define LOADB(X, RBASE)                                                     \
    {                                                                       \
        _Pragma("unroll")                                                   \
        for (int r = 0; r < 8; ++r) X[r] = fp[((RBASE) + r) * D4];          \
    }

#define PROCESS(X, RBASE)                                                   \
    {                                                                       \
        float ssq[8];                                                       \
        _Pragma("unroll")                                                   \
        for (int r = 0; r < 8; ++r) {                                       \
            const int lbl = lbls[(RBASE) + r];                              \
            const float4 c4 = *(const float4*)&cen[lbl * DIM + tid * 4];    \
            const float dx = X[r].x - c4.x, dy = X[r].y - c4.y;             \
            const float dz = X[r].z - c4.z, dw = X[r].w - c4.w;             \
            ssq[r] = fmaf(dx, dx, fmaf(dy, dy, fmaf(dz, dz, dw * dw)));     \
            _Pragma("unroll")                                               \
            for (int c = 0; c < NC; ++c) {                                  \
                const float kc = (lbl == c) ? 1.0f : 0.0f;                  \
                acc[c].x = fmaf(kc, X[r].x, acc[c].x);                      \
                acc[c].y = fmaf(kc, X[r].y, acc[c].y);                      \
                acc[c].z = fmaf(kc, X[r].z, acc[c].z);                      \
                acc[c].w = fmaf(kc, X[r].w, acc[c].w);                      \
            }                                                               \
        }                                                                   \
        _Pragma("unroll")                                                   \
        for (int o = 32; o > 0; o >>= 1) {                                  \
            _Pragma("unroll")                                               \
            for (int r = 0; r < 8; ++r) ssq[r] += __shfl_xor(ssq[r], o, 64);\
        }                                                                   \
        if (lane == 0) {                                                    \
            _Pragma("unroll")                                               \
            for (int r = 0; r < 8; ++r)                                     \
                partial[((RBASE) + r) * 4 + wid] = ssq[r];                  \
        }                                                                   \
    }

__global__ __launch_bounds__(BLK, 4)
void main_kernel(const float4* __restrict__ feats4,
                 const float*  __restrict__ labels,
                 const float4* __restrict__ centers4,
                 const float*  __restrict__ ws_ro,
                 float* __restrict__ featsum,
                 float* __restrict__ counts,
                 float* __restrict__ result) {
    __shared__ __align__(16) float cen[NC * DIM];   // 28 KB (reused for flush)
    __shared__ float partial[RPB * 4];              // 512 B
    __shared__ int   lbls[RPB];

    const int tid  = threadIdx.x;
    const int row0 = blockIdx.x * RPB;
    const int wid = tid >> 6, lane = tid & 63;

    const float4* fp = feats4 + (size_t)row0 * D4 + tid;

    // issue batch 0 loads first — overlaps LDS staging + barrier
    float4 xa[8], xb[8];
    LOADB(xa, 0);

    // stage centers into LDS
    for (int i = tid; i < NC * D4; i += BLK) ((float4*)cen)[i] = centers4[i];

    // decode one-hot labels for this block's rows
    if (tid < RPB) {
        const float* lr = labels + (size_t)(row0 + tid) * NC;
        int l = 0;
#pragma unroll
        for (int j = 1; j < NC; ++j) l = (lr[j] > 0.5f) ? j : l;
        lbls[tid] = l;
    }
    __syncthreads();

    const float pd = ws_ro[WS_PD];

    // per-class row counts (threads 0..6, registers)
    float mycnt = 0.0f;
    if (tid < NC) {
        for (int r = 0; r < RPB; ++r) mycnt += (lbls[r] == tid) ? 1.0f : 0.0f;
    }

    // register class accumulators
    float4 acc[NC];
#pragma unroll
    for (int c = 0; c < NC; ++c) acc[c] = make_float4(0.f, 0.f, 0.f, 0.f);

    // software-pipelined schedule: prefetch next batch, process current
    LOADB(xb, 8);
    PROCESS(xa, 0);
    LOADB(xa, 16);
    PROCESS(xb, 8);
    LOADB(xb, 24);
    PROCESS(xa, 16);
    PROCESS(xb, 24);
    __syncthreads();

    // finish per-row loss
    if (tid < RPB) {
        const float s = partial[tid * 4] + partial[tid * 4 + 1] +
                        partial[tid * 4 + 2] + partial[tid * 4 + 3];
        result[row0 + tid] = 0.5f * s + pd;
    }

    // stage register acc into (dead) cen LDS for a coalesced flush
    __syncthreads();   // everyone done reading cen
#pragma unroll
    for (int c = 0; c < NC; ++c)
        *(float4*)&cen[c * DIM + tid * 4] = acc[c];
    __syncthreads();

    // lane-consecutive 4B atomics (coalesced at L2/IF)
    for (int i = tid; i < NC * DIM; i += BLK) unsafeAtomicAdd(&featsum[i], cen[i]);
    if (tid < NC) unsafeAtomicAdd(&counts[tid], mycnt);
}

// ---------------------------------------------------------------------------
// Kernel 2: epilogue — new_centers (7x1024). One block per class.
// ---------------------------------------------------------------------------
__global__ __launch_bounds__(BLK)
void finish_kernel(const float4* __restrict__ centers4,
                   const float*  __restrict__ ws,
                   float4* __restrict__ outC) {
    const int c = blockIdx.x;
    const int t = threadIdx.x;

    const float cnt    = ws[WS_CNT + c];
    const float coef1  = ws[WS_COEF1 + c];
    const float rdenom = 1.0f / (cnt + 1.0f);
    const float KADD   = LAMBDA2_C / (float)(NC - 1);

    const float4 cen = centers4[c * D4 + t];
    const float4 fs  = ((const float4*)(ws + WS_FSUM))[c * D4 + t];

    float Tx = cen.x * coef1, Ty = cen.y * coef1, Tz = cen.z * coef1, Tw = cen.w * coef1;
#pragma unroll
    for (int m = 0; m < NC; ++m) {
        const float k2 = ws[WS_COEF2 + c * 7 + m];   // 0 on diagonal
        const float4 cm = centers4[m * D4 + t];
        Tx -= k2 * cm.x; Ty -= k2 * cm.y; Tz -= k2 * cm.z; Tw -= k2 * cm.w;
    }

    const float ox = cen.x - ALPHA_C * ((cnt * cen.x - fs.x) * rdenom) + KADD * Tx;
    const float oy = cen.y - ALPHA_C * ((cnt * cen.y - fs.y) * rdenom) + KADD * Ty;
    const float oz = cen.z - ALPHA_C * ((cnt * cen.z - fs.z) * rdenom) + KADD * Tz;
    const float ow = cen.w - ALPHA_C * ((cnt * cen.w - fs.w) * rdenom) + KADD * Tw;

    outC[c * D4 + t] = make_float4(ox, oy, oz, ow);
}

// ---------------------------------------------------------------------------
extern "C" void kernel_launch(void* const* d_in, const int* in_sizes, int n_in,
                              void* d_out, int out_size, void* d_ws, size_t ws_size,
                              hipStream_t stream) {
    const float* feats   = (const float*)d_in[0];   // (32768, 1024)
    const float* labels  = (const float*)d_in[1];   // (32768, 7) one-hot
    const float* centers = (const float*)d_in[2];   // (7, 1024)
    float* out = (float*)d_out;                     // [32768 result | 7168 new_centers]
    float* ws  = (float*)d_ws;

    prep_kernel<<<1, BLK, 0, stream>>>((const float4*)centers, ws);

    main_kernel<<<B_ROWS / RPB, BLK, 0, stream>>>(
        (const float4*)feats, labels, (const float4*)centers,
        ws, ws + WS_FSUM, ws + WS_CNT, out);

    finish_kernel<<<NC, BLK, 0, stream>>>(
        (const float4*)centers, ws, (float4*)(out + B_ROWS));
}

// Round 5
// 45.367 us; speedup vs baseline: 1.5807x; 1.5807x over previous
//
#include <hip/hip_runtime.h>
#include <math.h>

// Problem constants (hardcoded in the reference layer)
#define B_ROWS 32768
#define DIM    1024
#define NC     7
#define D4     (DIM/4)
#define RPB    64          // rows per block in the main pass
#define BLK    512         // 2 row-groups x 256 column-threads
#define PBLK   256         // prep/finish block size

#define ALPHA_C   0.5f
#define LAMBDA2_C 0.5f

// ws layout (floats):
//  [0]          pair_dist
//  [1..7]       coef1[7]
//  [8..56]      coef2[49]  (row-major, diag = 0)
//  [64..7231]   featsum[7*1024]
//  [7232..7238] counts[7] (float)
#define WS_PD     0
#define WS_COEF1  1
#define WS_COEF2  8
#define WS_FSUM   64
#define WS_CNT    (64 + NC*DIM)

__device__ __forceinline__ float waveReduceSum(float v) {
#pragma unroll
    for (int o = 32; o > 0; o >>= 1) v += __shfl_xor(v, o, 64);
    return v;
}

// Full wave64 sum via DPP (VALU-only, no DS pipe). Result valid in lane 63.
// rocPRIM sequence: row_shr:1,2,4,8 then row_bcast15, row_bcast31.
__device__ __forceinline__ float waveSum64_dpp(float v) {
#define DPP_ADD(CTRL)                                                        \
    v += __int_as_float(__builtin_amdgcn_update_dpp(                         \
        0, __float_as_int(v), CTRL, 0xF, 0xF, false))
    DPP_ADD(0x111);  // row_shr:1
    DPP_ADD(0x112);  // row_shr:2
    DPP_ADD(0x114);  // row_shr:4
    DPP_ADD(0x118);  // row_shr:8  -> lane15 of each row16 has row sum
    DPP_ADD(0x142);  // row_bcast15 -> lane31 = rows0+1, lane63 = rows2+3
    DPP_ADD(0x143);  // row_bcast31 -> lane63 = all 64 lanes
#undef DPP_ADD
    return v;
}

// ---------------------------------------------------------------------------
// Kernel 0: centers-only prologue. 1 block.
// ---------------------------------------------------------------------------
__global__ __launch_bounds__(PBLK)
void prep_kernel(const float4* __restrict__ centers4, float* __restrict__ ws) {
    __shared__ __align__(16) float cen[NC * DIM];
    __shared__ float G[NC * NC];
    const int tid = threadIdx.x;

    // zero the accumulation region (featsum + counts)
    for (int i = tid; i < NC * DIM + 8; i += PBLK) ws[WS_FSUM + i] = 0.0f;

    // stage centers into LDS
    for (int i = tid; i < NC * D4; i += PBLK) ((float4*)cen)[i] = centers4[i];
    __syncthreads();

    const int wid = tid >> 6, lane = tid & 63;
#pragma unroll 1
    for (int k = 0; k < 7; ++k) {
        const int p = wid * 7 + k;
        int j = 0, q = p;
        while (q >= 7 - j) { q -= 7 - j; ++j; }
        const int m = j + q;

        float s = 0.0f;
#pragma unroll
        for (int c4 = 0; c4 < 4; ++c4) {
            const float4 a = *(const float4*)&cen[j * DIM + (lane + c4 * 64) * 4];
            const float4 b = *(const float4*)&cen[m * DIM + (lane + c4 * 64) * 4];
            s += a.x * b.x + a.y * b.y + a.z * b.z + a.w * b.w;
        }
        s = waveReduceSum(s);
        if (lane == 0) { G[j * 7 + m] = s; G[m * 7 + j] = s; }
    }
    __syncthreads();

    if (tid == 0) {
        float inv[7], sumInv = 0.0f;
#pragma unroll
        for (int j = 0; j < 7; ++j) {
            inv[j] = 1.0f / sqrtf(G[j * 7 + j]);
            sumInv += inv[j];
        }
        float pdsum = 0.0f;
#pragma unroll
        for (int j = 0; j < 7; ++j) {
            ws[WS_COEF1 + j] = inv[j] * (sumInv - inv[j]);
#pragma unroll
            for (int m = 0; m < 7; ++m) {
                if (m == j) { ws[WS_COEF2 + j * 7 + m] = 0.0f; continue; }
                const float g = G[j * 7 + m];
                pdsum += g * inv[j] * inv[m] + 1.0f;
                ws[WS_COEF2 + j * 7 + m] = g * inv[j] * inv[m] * inv[m] * inv[m];
            }
        }
        ws[WS_PD] = LAMBDA2_C * pdsum;
    }
}

// ---------------------------------------------------------------------------
// Kernel 1: main streaming pass, 512 blocks x 64 rows (2 groups of 32).
//  - register class accumulators (7 float4, statically indexed)
//  - 8-row load batches (8 outstanding dwordx4 per wave)
//  - block-uniform label hoisted to SGPR via readfirstlane
//  - per-row sum: DPP wave reduce (VALU-only) + 1 LDS write from lane 63
//  - both groups' accs combined in LDS, ONE atomic flush pass per block
// ---------------------------------------------------------------------------
__global__ __launch_bounds__(BLK, 4)
void main_kernel(const float4* __restrict__ feats4,
                 const float*  __restrict__ labels,
                 const float4* __restrict__ centers4,
                 const float*  __restrict__ ws_ro,
                 float* __restrict__ featsum,
                 float* __restrict__ counts,
                 float* __restrict__ result) {
    __shared__ __align__(16) float cen[NC * DIM];   // 28 KB (reused for flush)
    __shared__ float partial[RPB * 4];              // 1 KB
    __shared__ int   lbls[RPB];

    const int tid  = threadIdx.x;
    const int g    = tid >> 8;          // row-group (0/1)
    const int ct   = tid & 255;         // column-thread within group
    const int lane = tid & 63;
    const int wgrp = (tid >> 6) & 3;    // wave within group
    const int row0 = blockIdx.x * RPB;

    // stage centers into LDS
    for (int i = tid; i < NC * D4; i += BLK) ((float4*)cen)[i] = centers4[i];

    // decode one-hot labels for this block's rows
    if (tid < RPB) {
        const float* lr = labels + (size_t)(row0 + tid) * NC;
        int l = 0;
#pragma unroll
        for (int j = 1; j < NC; ++j) l = (lr[j] > 0.5f) ? j : l;
        lbls[tid] = l;
    }
    __syncthreads();

    const float pd = ws_ro[WS_PD];

    // per-class row counts (threads 0..6, registers)
    float mycnt = 0.0f;
    if (tid < NC) {
        for (int r = 0; r < RPB; ++r) mycnt += (lbls[r] == tid) ? 1.0f : 0.0f;
    }

    // register class accumulators
    float4 acc[NC];
#pragma unroll
    for (int c = 0; c < NC; ++c) acc[c] = make_float4(0.f, 0.f, 0.f, 0.f);

    const float4* fp = feats4 + (size_t)(row0 + g * 32) * D4 + ct;

#pragma unroll 1
    for (int ch = 0; ch < 4; ++ch) {
        const int rb = ch * 8;                       // row offset within group
        // batched loads: 8 outstanding 16B loads
        float4 x[8];
#pragma unroll
        for (int r = 0; r < 8; ++r) x[r] = fp[(rb + r) * D4];

#pragma unroll
        for (int r = 0; r < 8; ++r) {
            const int lbl = __builtin_amdgcn_readfirstlane(lbls[g * 32 + rb + r]);
            const float4 c4 = *(const float4*)&cen[lbl * DIM + ct * 4];
            const float dx = x[r].x - c4.x, dy = x[r].y - c4.y;
            const float dz = x[r].z - c4.z, dw = x[r].w - c4.w;
            float ssq = fmaf(dx, dx, fmaf(dy, dy, fmaf(dz, dz, dw * dw)));
#pragma unroll
            for (int c = 0; c < NC; ++c) {
                const float kc = (lbl == c) ? 1.0f : 0.0f;   // SALU select (lbl is SGPR)
                acc[c].x = fmaf(kc, x[r].x, acc[c].x);
                acc[c].y = fmaf(kc, x[r].y, acc[c].y);
                acc[c].z = fmaf(kc, x[r].z, acc[c].z);
                acc[c].w = fmaf(kc, x[r].w, acc[c].w);
            }
            ssq = waveSum64_dpp(ssq);                        // VALU-only reduce
            if (lane == 63) partial[(g * 32 + rb + r) * 4 + wgrp] = ssq;
        }
    }
    __syncthreads();

    // finish per-row loss
    if (tid < RPB) {
        const float s = partial[tid * 4] + partial[tid * 4 + 1] +
                        partial[tid * 4 + 2] + partial[tid * 4 + 3];
        result[row0 + tid] = 0.5f * s + pd;
    }

    // combine both groups' register accs in (dead) cen LDS, then one flush
    if (g == 0) {
#pragma unroll
        for (int c = 0; c < NC; ++c)
            *(float4*)&cen[c * DIM + ct * 4] = acc[c];
    }
    __syncthreads();
    if (g == 1) {
#pragma unroll
        for (int c = 0; c < NC; ++c) {
            float4 t = *(const float4*)&cen[c * DIM + ct * 4];
            t.x += acc[c].x; t.y += acc[c].y; t.z += acc[c].z; t.w += acc[c].w;
            *(float4*)&cen[c * DIM + ct * 4] = t;
        }
    }
    __syncthreads();

    // lane-consecutive 4B atomics (coalesced at L2/IF)
    for (int i = tid; i < NC * DIM; i += BLK) unsafeAtomicAdd(&featsum[i], cen[i]);
    if (tid < NC) unsafeAtomicAdd(&counts[tid], mycnt);
}

// ---------------------------------------------------------------------------
// Kernel 2: epilogue — new_centers (7x1024). One block per class.
// ---------------------------------------------------------------------------
__global__ __launch_bounds__(PBLK)
void finish_kernel(const float4* __restrict__ centers4,
                   const float*  __restrict__ ws,
                   float4* __restrict__ outC) {
    const int c = blockIdx.x;
    const int t = threadIdx.x;

    const float cnt    = ws[WS_CNT + c];
    const float coef1  = ws[WS_COEF1 + c];
    const float rdenom = 1.0f / (cnt + 1.0f);
    const float KADD   = LAMBDA2_C / (float)(NC - 1);

    const float4 cen = centers4[c * D4 + t];
    const float4 fs  = ((const float4*)(ws + WS_FSUM))[c * D4 + t];

    float Tx = cen.x * coef1, Ty = cen.y * coef1, Tz = cen.z * coef1, Tw = cen.w * coef1;
#pragma unroll
    for (int m = 0; m < NC; ++m) {
        const float k2 = ws[WS_COEF2 + c * 7 + m];   // 0 on diagonal
        const float4 cm = centers4[m * D4 + t];
        Tx -= k2 * cm.x; Ty -= k2 * cm.y; Tz -= k2 * cm.z; Tw -= k2 * cm.w;
    }

    const float ox = cen.x - ALPHA_C * ((cnt * cen.x - fs.x) * rdenom) + KADD * Tx;
    const float oy = cen.y - ALPHA_C * ((cnt * cen.y - fs.y) * rdenom) + KADD * Ty;
    const float oz = cen.z - ALPHA_C * ((cnt * cen.z - fs.z) * rdenom) + KADD * Tz;
    const float ow = cen.w - ALPHA_C * ((cnt * cen.w - fs.w) * rdenom) + KADD * Tw;

    outC[c * D4 + t] = make_float4(ox, oy, oz, ow);
}

// ---------------------------------------------------------------------------
extern "C" void kernel_launch(void* const* d_in, const int* in_sizes, int n_in,
                              void* d_out, int out_size, void* d_ws, size_t ws_size,
                              hipStream_t stream) {
    const float* feats   = (const float*)d_in[0];   // (32768, 1024)
    const float* labels  = (const float*)d_in[1];   // (32768, 7) one-hot
    const float* centers = (const float*)d_in[2];   // (7, 1024)
    float* out = (float*)d_out;                     // [32768 result | 7168 new_centers]
    float* ws  = (float*)d_ws;

    prep_kernel<<<1, PBLK, 0, stream>>>((const float4*)centers, ws);

    main_kernel<<<B_ROWS / RPB, BLK, 0, stream>>>(
        (const float4*)feats, labels, (const float4*)centers,
        ws, ws + WS_FSUM, ws + WS_CNT, out);

    finish_kernel<<<NC, PBLK, 0, stream>>>(
        (const float4*)centers, ws, (float4*)(out + B_ROWS));
}